// Round 1
// baseline (150562.732 us; speedup 1.0000x reference)
//
#include <hip/hip_runtime.h>

// NCDE classifier: B=512 chains, T=2048 steps, D=32, M=64, W=128.
// Design: 256 blocks = 32 clusters (16 chains each) x 8 model-slices.
// Each block keeps its W2 slice (256 rows x 128, f16, XOR-swizzled) resident in LDS,
// W0/W1 as MFMA B-fragments in registers. Per g-eval the cluster exchanges the
// 16x8 y-slice through a global buffer with a monotone counter barrier.

#define TT 2048
#define NTH 512

typedef _Float16 f16;
typedef _Float16 f16x8 __attribute__((ext_vector_type(8)));
typedef float f32x4 __attribute__((ext_vector_type(4)));

// LDS layout (bytes)
#define O_W2   0        // 256*128 f16 swizzled = 65536
#define O_H1   65536    // 16*128 f16 = 4096
#define O_H2   69632    // 16*128 f16 = 4096
#define O_YIN  73728    // 16*64 f16 = 2048
#define O_B0   75776    // 128 f32
#define O_B1   76288    // 128 f32
#define O_B2   76800    // 256 f32
#define O_DXDT 77824    // 16*36 f32 = 2304
#define O_GP   80128    // 2*4*16*9 f32 = 4608
#define O_XPRV 84736    // 16*32 f32 = 2048
#define O_YB   86784    // 16*8 f32 = 512
#define O_KA   87296    // 16*8 f32 = 512
#define LDSB   87808

__device__ __forceinline__ float tanh_fast(float x){
    float e = __expf(2.0f * x);
    return 1.0f - 2.0f * __builtin_amdgcn_rcpf(e + 1.0f);
}
__device__ __forceinline__ float gelu_f(float x){
    float u = x + 0.044715f * x * x * x;
    return 0.5f * x * (1.0f + tanh_fast(0.7978845608028654f * u));
}
// xor1 / xor2 within quads via DPP (VALU, keeps LDS pipe free)
__device__ __forceinline__ float dpp_add_xor1(float p){
    int v = __builtin_amdgcn_update_dpp(0, __float_as_int(p), 0xB1, 0xF, 0xF, true);
    return p + __int_as_float(v);
}
__device__ __forceinline__ float dpp_add_xor2(float p){
    int v = __builtin_amdgcn_update_dpp(0, __float_as_int(p), 0x4E, 0xF, 0xF, true);
    return p + __int_as_float(v);
}

__global__ void __launch_bounds__(NTH)
ncde_main(const float* __restrict__ times, const float* __restrict__ xs,
          const float* __restrict__ eW0, const float* __restrict__ eb0,
          const float* __restrict__ eW1, const float* __restrict__ eb1,
          const float* __restrict__ eW2, const float* __restrict__ eb2,
          const float* __restrict__ vW0, const float* __restrict__ vW1,
          const float* __restrict__ vb0, const float* __restrict__ vb1,
          const float* __restrict__ vW2, const float* __restrict__ vb2,
          const float* __restrict__ dW,
          float* __restrict__ logits, unsigned* __restrict__ ctrs,
          float* __restrict__ gbuf)
{
    extern __shared__ char lds[];
    float* b0f  = (float*)(lds + O_B0);
    float* b1f  = (float*)(lds + O_B1);
    float* b2s  = (float*)(lds + O_B2);
    float* dxdt = (float*)(lds + O_DXDT);   // [16][36]
    float* gpart= (float*)(lds + O_GP);     // [2][4][16][9]
    float* xprv = (float*)(lds + O_XPRV);   // [16][32]
    float* yb   = (float*)(lds + O_YB);     // [16][8]
    float* kacc = (float*)(lds + O_KA);     // [16][8]
    float* enc1 = (float*)(lds + 0);        // [16][128] (aliases W2 region, pre-fill only)
    float* enc2 = (float*)(lds + 8192);     // [16][128]

    const int tid = threadIdx.x;
    const int l   = tid & 63;
    const int w   = tid >> 6;          // wave 0..7
    const int bid = blockIdx.x;
    const int q   = bid & 31;          // cluster (chains)
    const int s   = bid >> 5;          // slice 0..7
    const int c0  = q << 4;

    if (tid < 128){ b0f[tid] = vb0[tid]; b1f[tid] = vb1[tid]; }
    if (tid < 256){ b2s[tid] = vb2[s*256 + tid]; }
    {   int r = tid >> 5, d = tid & 31;
        xprv[r*32 + d] = xs[((size_t)(c0 + r) * TT) * 32 + d];
    }
    __syncthreads();

    // ---- encoder (fp32, redundant per block) ----
    for (int i = tid; i < 16*128; i += NTH){
        int r = i >> 7, n = i & 127;
        float a = eb0[n];
        #pragma unroll
        for (int k = 0; k < 32; ++k) a += eW0[n*32 + k] * xprv[r*32 + k];
        enc1[i] = fmaxf(a, 0.f);
    }
    __syncthreads();
    for (int i = tid; i < 16*128; i += NTH){
        int r = i >> 7, n = i & 127;
        float a = eb1[n];
        for (int k = 0; k < 128; ++k) a += eW1[n*128 + k] * enc1[r*128 + k];
        enc2[i] = fmaxf(a, 0.f);
    }
    __syncthreads();
    for (int i = tid; i < 16*64; i += NTH){
        int r = i >> 6, m = i & 63;
        float a = eb2[m];
        for (int k = 0; k < 128; ++k) a += eW2[m*128 + k] * enc2[r*128 + k];
        int off = (m*2) ^ ((r & 7) << 4);
        *(f16*)(lds + O_YIN + r*128 + off) = (f16)a;
        int lm = m - (s << 3);
        if (0 <= lm && lm < 8) yb[r*8 + lm] = a;
    }
    __syncthreads();

    // ---- W0/W1 fragments into registers (B operand: col = l&15, k = 8*(l>>4)+i) ----
    f16x8 w0f[2], w1f[4];
    {
        int col  = (w << 4) + (l & 15);
        int krow = (l >> 4) << 3;
        #pragma unroll
        for (int ks = 0; ks < 2; ++ks){
            const float* p = vW0 + col*64 + ks*32 + krow;
            f16x8 v;
            #pragma unroll
            for (int i = 0; i < 8; ++i) v[i] = (f16)p[i];
            w0f[ks] = v;
        }
        #pragma unroll
        for (int ks = 0; ks < 4; ++ks){
            const float* p = vW1 + col*128 + ks*32 + krow;
            f16x8 v;
            #pragma unroll
            for (int i = 0; i < 8; ++i) v[i] = (f16)p[i];
            w1f[ks] = v;
        }
    }
    // ---- W2 slice -> LDS (f16, swizzled rows of 256B) ----
    for (int idx = tid; idx < 4096; idx += NTH){
        int n = idx >> 4, c = idx & 15;
        const float* p = vW2 + (size_t)(s*256 + n)*128 + c*8;
        f16x8 v;
        #pragma unroll
        for (int i = 0; i < 8; ++i) v[i] = (f16)p[i];
        int off = (c*16) ^ ((n & 7) << 4);
        *(f16x8*)(lds + O_W2 + n*256 + off) = v;
    }
    __syncthreads();

    const int arow = l & 15;
    const int akb  = (l >> 4) << 3;

    unsigned gath = 0;
    for (int t = 0; t < TT-1; ++t){
        float dtv = times[t+1] - times[t];
        {   int r = tid >> 5, d = tid & 31;
            float xn = xs[((size_t)(c0 + r) * TT + (t+1)) * 32 + d];
            float xp = xprv[r*32 + d];
            dxdt[r*36 + d] = (xn - xp) / dtv;
            xprv[r*32 + d] = xn;
        }
        if (tid < 128) kacc[tid] = 0.f;
        __syncthreads();

        #pragma unroll 1
        for (int st = 0; st < 4; ++st){
            // ---- L1: yin(16x64) @ W0^T -> h1(16x128), gelu ----
            {
                f32x4 acc = {0.f,0.f,0.f,0.f};
                #pragma unroll
                for (int ks = 0; ks < 2; ++ks){
                    int k = ks*32 + akb;
                    f16x8 a = *(const f16x8*)(lds + O_YIN + arow*128 + ((k*2) ^ ((arow & 7) << 4)));
                    acc = __builtin_amdgcn_mfma_f32_16x16x32_f16(a, w0f[ks], acc, 0, 0, 0);
                }
                int col = (w << 4) + (l & 15);
                float bb = b0f[col];
                #pragma unroll
                for (int j = 0; j < 4; ++j){
                    int row = ((l >> 4) << 2) + j;
                    float g = gelu_f(acc[j] + bb);
                    *(f16*)(lds + O_H1 + row*256 + ((col*2) ^ ((row & 7) << 4))) = (f16)g;
                }
            }
            __syncthreads();
            // ---- L2: h1 @ W1^T -> h2(16x128), gelu ----
            {
                f32x4 acc = {0.f,0.f,0.f,0.f};
                #pragma unroll
                for (int ks = 0; ks < 4; ++ks){
                    int k = ks*32 + akb;
                    f16x8 a = *(const f16x8*)(lds + O_H1 + arow*256 + ((k*2) ^ ((arow & 7) << 4)));
                    acc = __builtin_amdgcn_mfma_f32_16x16x32_f16(a, w1f[ks], acc, 0, 0, 0);
                }
                int col = (w << 4) + (l & 15);
                float bb = b1f[col];
                #pragma unroll
                for (int j = 0; j < 4; ++j){
                    int row = ((l >> 4) << 2) + j;
                    float g = gelu_f(acc[j] + bb);
                    *(f16*)(lds + O_H2 + row*256 + ((col*2) ^ ((row & 7) << 4))) = (f16)g;
                }
            }
            __syncthreads();
            // ---- L3 slice: h2 @ W2s^T -> tanh -> * dXdt -> partial g ----
            {
                f16x8 a3[4];
                #pragma unroll
                for (int ks = 0; ks < 4; ++ks){
                    int k = ks*32 + akb;
                    a3[ks] = *(const f16x8*)(lds + O_H2 + arow*256 + ((k*2) ^ ((arow & 7) << 4)));
                }
                #pragma unroll
                for (int tt = 0; tt < 2; ++tt){
                    int tile = (w << 1) + tt;     // lm = w, dhalf = tt
                    int dh = tile & 1;
                    int n = (tile << 4) + (l & 15);
                    f32x4 c3 = {0.f,0.f,0.f,0.f};
                    #pragma unroll
                    for (int ks = 0; ks < 4; ++ks){
                        int k = ks*32 + akb;
                        f16x8 b = *(const f16x8*)(lds + O_W2 + n*256 + ((k*2) ^ ((n & 7) << 4)));
                        c3 = __builtin_amdgcn_mfma_f32_16x16x32_f16(a3[ks], b, c3, 0, 0, 0);
                    }
                    float bb = b2s[n];
                    int d = (dh << 4) + (l & 15);
                    #pragma unroll
                    for (int j = 0; j < 4; ++j){
                        int row = ((l >> 4) << 2) + j;
                        float p = tanh_fast(c3[j] + bb) * dxdt[row*36 + d];
                        p = dpp_add_xor1(p);
                        p = dpp_add_xor2(p);
                        if ((l & 3) == 0){
                            int dq = (l >> 2) & 3;
                            gpart[((dh*4 + dq)*16 + row)*9 + w] = p;
                        }
                    }
                }
            }
            __syncthreads();
            // ---- combine + RK4 update (owner threads) ----
            float ynext = 0.f;
            if (tid < 128){
                int r = tid >> 3, lm = tid & 7;
                float kv = 0.f;
                #pragma unroll
                for (int dh = 0; dh < 2; ++dh)
                    #pragma unroll
                    for (int dq = 0; dq < 4; ++dq)
                        kv += gpart[((dh*4 + dq)*16 + r)*9 + lm];
                float wgt = (st == 1 || st == 2) ? 2.f : 1.f;
                float ka = kacc[tid] + wgt * kv;
                kacc[tid] = ka;
                if (st < 3){
                    float cs = (st == 2) ? 1.0f : 0.5f;
                    ynext = yb[tid] + cs * dtv * kv;
                } else {
                    float yn = yb[tid] + (dtv / 6.0f) * ka;
                    yb[tid] = yn;
                    ynext = yn;
                }
            }
            bool last = (t == TT-2) && (st == 3);
            if (!last){
                int par = (int)(gath & 1u);
                if (tid < 128){
                    gbuf[(((q << 3) + s)*2 + par)*128 + tid] = ynext;
                    __threadfence();
                }
                __syncthreads();
                ++gath;
                if (tid == 0){
                    __hip_atomic_fetch_add(&ctrs[q], 1u, __ATOMIC_RELEASE, __HIP_MEMORY_SCOPE_AGENT);
                    unsigned target = gath * 8u;
                    while (__hip_atomic_load(&ctrs[q], __ATOMIC_ACQUIRE, __HIP_MEMORY_SCOPE_AGENT) < target)
                        __builtin_amdgcn_s_sleep(1);
                }
                __syncthreads();
                // rebuild yin (f16, swizzled) from all 8 slices
                {
                    int r = tid >> 5, mp = tid & 31;
                    int sl = mp >> 2;
                    int lmb = (mp & 3) << 1;
                    float* src = gbuf + (((q << 3) + sl)*2 + par)*128 + r*8 + lmb;
                    float f0 = __hip_atomic_load(src,     __ATOMIC_RELAXED, __HIP_MEMORY_SCOPE_AGENT);
                    float f1 = __hip_atomic_load(src + 1, __ATOMIC_RELAXED, __HIP_MEMORY_SCOPE_AGENT);
                    union { f16 h[2]; unsigned u; } pk;
                    pk.h[0] = (f16)f0; pk.h[1] = (f16)f1;
                    int off = (mp*4) ^ ((r & 7) << 4);
                    *(unsigned*)(lds + O_YIN + r*128 + off) = pk.u;
                }
                __syncthreads();
            }
        } // stages
    } // t

    // ---- decoder partial: sum over this slice's 8 model dims ----
    if (tid < 128){
        int r = tid >> 3, lm = tid & 7;
        float p = yb[tid] * dW[(s << 3) + lm];
        p += __shfl_xor(p, 1);
        p += __shfl_xor(p, 2);
        p += __shfl_xor(p, 4);
        if (lm == 0) atomicAdd(&logits[c0 + r], p);
    }
}

__global__ void ncde_fin(const float* __restrict__ logits,
                         const float* __restrict__ db,
                         float* __restrict__ out)
{
    int i = threadIdx.x;
    if (i < 512){
        float x = logits[i] + db[0];
        out[i] = 1.0f / (1.0f + __expf(-x));
    }
}

extern "C" void kernel_launch(void* const* d_in, const int* in_sizes, int n_in,
                              void* d_out, int out_size, void* d_ws, size_t ws_size,
                              hipStream_t stream)
{
    const float* times = (const float*)d_in[0];
    const float* xs    = (const float*)d_in[1];
    const float* eW0   = (const float*)d_in[2];
    const float* eb0   = (const float*)d_in[3];
    const float* eW1   = (const float*)d_in[4];
    const float* eb1   = (const float*)d_in[5];
    const float* eW2   = (const float*)d_in[6];
    const float* eb2   = (const float*)d_in[7];
    const float* vW0   = (const float*)d_in[8];
    const float* vb0   = (const float*)d_in[9];
    const float* vW1   = (const float*)d_in[10];
    const float* vb1   = (const float*)d_in[11];
    const float* vW2   = (const float*)d_in[12];
    const float* vb2   = (const float*)d_in[13];
    const float* dW    = (const float*)d_in[14];
    const float* db    = (const float*)d_in[15];

    float*    logits = (float*)d_ws;                       // 512 f32
    unsigned* ctrs   = (unsigned*)((char*)d_ws + 2048);    // 32 u32
    float*    gbuf   = (float*)((char*)d_ws + 4096);       // 256 KB exchange

    hipMemsetAsync(d_ws, 0, 4096, stream);
    hipFuncSetAttribute((const void*)ncde_main,
                        hipFuncAttributeMaxDynamicSharedMemorySize, LDSB);

    ncde_main<<<dim3(256), dim3(NTH), LDSB, stream>>>(
        times, xs, eW0, eb0, eW1, eb1, eW2, eb2,
        vW0, vW1, vb0, vb1, vW2, vb2, dW,
        logits, ctrs, gbuf);
    ncde_fin<<<dim3(1), dim3(512), 0, stream>>>(logits, db, (float*)d_out);
}

// Round 3
// 91421.088 us; speedup vs baseline: 1.6469x; 1.6469x over previous
//
#include <hip/hip_runtime.h>

// NCDE classifier: B=512 chains, T=2048 steps, D=32, M=64, W=128.
// 256 blocks = 32 clusters (16 chains each) x 8 model-slices.
// W2 slice (256x128 f16, XOR-swizzled) LDS-resident; W0/W1 as register B-fragments.
// Per g-eval the cluster exchanges the 16x8 y-slice via L2 with per-slice
// monotone flags (128B-padded, write-only; no contended RMW).

#define TT 2048
#define NTH 512

typedef _Float16 f16;
typedef _Float16 f16x8 __attribute__((ext_vector_type(8)));
typedef float f32x4 __attribute__((ext_vector_type(4)));

// LDS layout (bytes)
#define O_W2   0        // 256*128 f16 swizzled = 65536
#define O_H1   65536    // 16*128 f16 = 4096
#define O_H2   69632    // 16*128 f16 = 4096
#define O_YIN  73728    // 16*64 f16 = 2048
#define O_B0   75776    // 128 f32
#define O_B1   76288    // 128 f32
#define O_B2   76800    // 256 f32
#define O_DXDT 77824    // 16*36 f32 = 2304
#define O_GP   80128    // 2*4*16*9 f32 = 4608
#define O_XPRV 84736    // 16*32 f32 = 2048
#define O_YB   86784    // 16*8 f32 = 512
#define O_KA   87296    // 16*8 f32 = 512
#define LDSB   87808

__device__ __forceinline__ float tanh_fast(float x){
    float e = __expf(2.0f * x);
    return 1.0f - 2.0f * __builtin_amdgcn_rcpf(e + 1.0f);
}
__device__ __forceinline__ float gelu_f(float x){
    float u = x + 0.044715f * x * x * x;
    return 0.5f * x * (1.0f + tanh_fast(0.7978845608028654f * u));
}
__device__ __forceinline__ float dpp_add_xor1(float p){
    int v = __builtin_amdgcn_update_dpp(0, __float_as_int(p), 0xB1, 0xF, 0xF, true);
    return p + __int_as_float(v);
}
__device__ __forceinline__ float dpp_add_xor2(float p){
    int v = __builtin_amdgcn_update_dpp(0, __float_as_int(p), 0x4E, 0xF, 0xF, true);
    return p + __int_as_float(v);
}

__global__ void __launch_bounds__(NTH)
ncde_main(const float* __restrict__ times, const float* __restrict__ xs,
          const float* __restrict__ eW0, const float* __restrict__ eb0,
          const float* __restrict__ eW1, const float* __restrict__ eb1,
          const float* __restrict__ eW2, const float* __restrict__ eb2,
          const float* __restrict__ vW0, const float* __restrict__ vW1,
          const float* __restrict__ vb0, const float* __restrict__ vb1,
          const float* __restrict__ vW2, const float* __restrict__ vb2,
          const float* __restrict__ dW,
          float* __restrict__ logits, unsigned* __restrict__ flags,
          float* __restrict__ gbuf)
{
    extern __shared__ char lds[];
    float* b0f  = (float*)(lds + O_B0);
    float* b1f  = (float*)(lds + O_B1);
    float* b2s  = (float*)(lds + O_B2);
    float* dxdt = (float*)(lds + O_DXDT);   // [16][36]
    float* gpart= (float*)(lds + O_GP);     // [2][4][16][9]
    float* xprv = (float*)(lds + O_XPRV);   // [16][32]
    float* yb   = (float*)(lds + O_YB);     // [16][8]
    float* kacc = (float*)(lds + O_KA);     // [16][8]
    float* enc1 = (float*)(lds + 0);        // [16][128] (aliases W2 region, pre-fill only)
    float* enc2 = (float*)(lds + 8192);     // [16][128]

    const int tid = threadIdx.x;
    const int l   = tid & 63;
    const int w   = tid >> 6;          // wave 0..7
    const int bid = blockIdx.x;
    const int q   = bid & 31;          // cluster (chains); members share bid%8 -> same XCD
    const int s   = bid >> 5;          // slice 0..7
    const int c0  = q << 4;

    if (tid < 128){ b0f[tid] = vb0[tid]; b1f[tid] = vb1[tid]; }
    if (tid < 256){ b2s[tid] = vb2[s*256 + tid]; }
    {   int r = tid >> 5, d = tid & 31;
        xprv[r*32 + d] = xs[((size_t)(c0 + r) * TT) * 32 + d];
    }
    __syncthreads();

    // ---- encoder (fp32, redundant per block) ----
    for (int i = tid; i < 16*128; i += NTH){
        int r = i >> 7, n = i & 127;
        float a = eb0[n];
        #pragma unroll
        for (int k = 0; k < 32; ++k) a += eW0[n*32 + k] * xprv[r*32 + k];
        enc1[i] = fmaxf(a, 0.f);
    }
    __syncthreads();
    for (int i = tid; i < 16*128; i += NTH){
        int r = i >> 7, n = i & 127;
        float a = eb1[n];
        for (int k = 0; k < 128; ++k) a += eW1[n*128 + k] * enc1[r*128 + k];
        enc2[i] = fmaxf(a, 0.f);
    }
    __syncthreads();
    for (int i = tid; i < 16*64; i += NTH){
        int r = i >> 6, m = i & 63;
        float a = eb2[m];
        for (int k = 0; k < 128; ++k) a += eW2[m*128 + k] * enc2[r*128 + k];
        int off = (m*2) ^ ((r & 7) << 4);
        *(f16*)(lds + O_YIN + r*128 + off) = (f16)a;
        int lm = m - (s << 3);
        if (0 <= lm && lm < 8) yb[r*8 + lm] = a;
    }
    __syncthreads();

    // ---- W0/W1 fragments into registers (B operand: col = l&15, k = 8*(l>>4)+i) ----
    f16x8 w0f[2], w1f[4];
    {
        int col  = (w << 4) + (l & 15);
        int krow = (l >> 4) << 3;
        #pragma unroll
        for (int ks = 0; ks < 2; ++ks){
            const float* p = vW0 + col*64 + ks*32 + krow;
            f16x8 v;
            #pragma unroll
            for (int i = 0; i < 8; ++i) v[i] = (f16)p[i];
            w0f[ks] = v;
        }
        #pragma unroll
        for (int ks = 0; ks < 4; ++ks){
            const float* p = vW1 + col*128 + ks*32 + krow;
            f16x8 v;
            #pragma unroll
            for (int i = 0; i < 8; ++i) v[i] = (f16)p[i];
            w1f[ks] = v;
        }
    }
    // ---- W2 slice -> LDS (f16, swizzled rows of 256B) ----
    for (int idx = tid; idx < 4096; idx += NTH){
        int n = idx >> 4, c = idx & 15;
        const float* p = vW2 + (size_t)(s*256 + n)*128 + c*8;
        f16x8 v;
        #pragma unroll
        for (int i = 0; i < 8; ++i) v[i] = (f16)p[i];
        int off = (c*16) ^ ((n & 7) << 4);
        *(f16x8*)(lds + O_W2 + n*256 + off) = v;
    }
    __syncthreads();

    const int arow = l & 15;
    const int akb  = (l >> 4) << 3;

    unsigned gath = 0;
    for (int t = 0; t < TT-1; ++t){
        float dtv = times[t+1] - times[t];
        {   int r = tid >> 5, d = tid & 31;
            float xn = xs[((size_t)(c0 + r) * TT + (t+1)) * 32 + d];
            float xp = xprv[r*32 + d];
            dxdt[r*36 + d] = (xn - xp) / dtv;
            xprv[r*32 + d] = xn;
        }
        if (tid < 128) kacc[tid] = 0.f;
        __syncthreads();

        #pragma unroll 1
        for (int st = 0; st < 4; ++st){
            // ---- L1: yin(16x64) @ W0^T -> h1(16x128), gelu ----
            {
                f32x4 acc = {0.f,0.f,0.f,0.f};
                #pragma unroll
                for (int ks = 0; ks < 2; ++ks){
                    int k = ks*32 + akb;
                    f16x8 a = *(const f16x8*)(lds + O_YIN + arow*128 + ((k*2) ^ ((arow & 7) << 4)));
                    acc = __builtin_amdgcn_mfma_f32_16x16x32_f16(a, w0f[ks], acc, 0, 0, 0);
                }
                int col = (w << 4) + (l & 15);
                float bb = b0f[col];
                #pragma unroll
                for (int j = 0; j < 4; ++j){
                    int row = ((l >> 4) << 2) + j;
                    float g = gelu_f(acc[j] + bb);
                    *(f16*)(lds + O_H1 + row*256 + ((col*2) ^ ((row & 7) << 4))) = (f16)g;
                }
            }
            __syncthreads();
            // ---- L2: h1 @ W1^T -> h2(16x128), gelu ----
            {
                f32x4 acc = {0.f,0.f,0.f,0.f};
                #pragma unroll
                for (int ks = 0; ks < 4; ++ks){
                    int k = ks*32 + akb;
                    f16x8 a = *(const f16x8*)(lds + O_H1 + arow*256 + ((k*2) ^ ((arow & 7) << 4)));
                    acc = __builtin_amdgcn_mfma_f32_16x16x32_f16(a, w1f[ks], acc, 0, 0, 0);
                }
                int col = (w << 4) + (l & 15);
                float bb = b1f[col];
                #pragma unroll
                for (int j = 0; j < 4; ++j){
                    int row = ((l >> 4) << 2) + j;
                    float g = gelu_f(acc[j] + bb);
                    *(f16*)(lds + O_H2 + row*256 + ((col*2) ^ ((row & 7) << 4))) = (f16)g;
                }
            }
            __syncthreads();
            // ---- L3 slice: h2 @ W2s^T -> tanh -> * dXdt -> partial g ----
            {
                f16x8 a3[4];
                #pragma unroll
                for (int ks = 0; ks < 4; ++ks){
                    int k = ks*32 + akb;
                    a3[ks] = *(const f16x8*)(lds + O_H2 + arow*256 + ((k*2) ^ ((arow & 7) << 4)));
                }
                #pragma unroll
                for (int tt = 0; tt < 2; ++tt){
                    int tile = (w << 1) + tt;
                    int dh = tile & 1;
                    int n = (tile << 4) + (l & 15);
                    f32x4 c3 = {0.f,0.f,0.f,0.f};
                    #pragma unroll
                    for (int ks = 0; ks < 4; ++ks){
                        int k = ks*32 + akb;
                        f16x8 b = *(const f16x8*)(lds + O_W2 + n*256 + ((k*2) ^ ((n & 7) << 4)));
                        c3 = __builtin_amdgcn_mfma_f32_16x16x32_f16(a3[ks], b, c3, 0, 0, 0);
                    }
                    float bb = b2s[n];
                    int d = (dh << 4) + (l & 15);
                    #pragma unroll
                    for (int j = 0; j < 4; ++j){
                        int row = ((l >> 4) << 2) + j;
                        float p = tanh_fast(c3[j] + bb) * dxdt[row*36 + d];
                        p = dpp_add_xor1(p);
                        p = dpp_add_xor2(p);
                        if ((l & 3) == 0){
                            int dq = (l >> 2) & 3;
                            gpart[((dh*4 + dq)*16 + row)*9 + w] = p;
                        }
                    }
                }
            }
            __syncthreads();
            // ---- combine + RK4 update (owner threads) ----
            float ynext = 0.f;
            if (tid < 128){
                int r = tid >> 3, lm = tid & 7;
                float kv = 0.f;
                #pragma unroll
                for (int dh = 0; dh < 2; ++dh)
                    #pragma unroll
                    for (int dq = 0; dq < 4; ++dq)
                        kv += gpart[((dh*4 + dq)*16 + r)*9 + lm];
                float wgt = (st == 1 || st == 2) ? 2.f : 1.f;
                float ka = kacc[tid] + wgt * kv;
                kacc[tid] = ka;
                if (st < 3){
                    float cs = (st == 2) ? 1.0f : 0.5f;
                    ynext = yb[tid] + cs * dtv * kv;
                } else {
                    float yn = yb[tid] + (dtv / 6.0f) * ka;
                    yb[tid] = yn;
                    ynext = yn;
                }
            }
            bool last = (t == TT-2) && (st == 3);
            if (!last){
                int par = (int)(gath & 1u);
                if (tid < 128){
                    __hip_atomic_store(&gbuf[(((q << 3) + s)*2 + par)*128 + tid], ynext,
                                       __ATOMIC_RELAXED, __HIP_MEMORY_SCOPE_AGENT);
                }
                __syncthreads();   // drains vmcnt: data stores complete at L2
                ++gath;
                if (tid == 0){
                    __threadfence();   // single-thread flush before flag
                    __hip_atomic_store(&flags[((q << 3) + s) * 32], gath,
                                       __ATOMIC_RELEASE, __HIP_MEMORY_SCOPE_AGENT);
                }
                if (tid < 8){
                    while (__hip_atomic_load(&flags[((q << 3) + tid) * 32],
                                             __ATOMIC_ACQUIRE, __HIP_MEMORY_SCOPE_AGENT) < gath)
                        __builtin_amdgcn_s_sleep(1);
                }
                __syncthreads();
                // rebuild yin (f16, swizzled) from all 8 slices
                {
                    int r = tid >> 5, mp = tid & 31;
                    int sl = mp >> 2;
                    int lmb = (mp & 3) << 1;
                    float* src = gbuf + (((q << 3) + sl)*2 + par)*128 + r*8 + lmb;
                    float f0 = __hip_atomic_load(src,     __ATOMIC_RELAXED, __HIP_MEMORY_SCOPE_AGENT);
                    float f1 = __hip_atomic_load(src + 1, __ATOMIC_RELAXED, __HIP_MEMORY_SCOPE_AGENT);
                    union { f16 h[2]; unsigned u; } pk;
                    pk.h[0] = (f16)f0; pk.h[1] = (f16)f1;
                    int off = (mp*4) ^ ((r & 7) << 4);
                    *(unsigned*)(lds + O_YIN + r*128 + off) = pk.u;
                }
                __syncthreads();
            }
        } // stages
    } // t

    // ---- decoder partial: sum over this slice's 8 model dims ----
    if (tid < 128){
        int r = tid >> 3, lm = tid & 7;
        float p = yb[tid] * dW[(s << 3) + lm];
        p += __shfl_xor(p, 1);
        p += __shfl_xor(p, 2);
        p += __shfl_xor(p, 4);
        if (lm == 0) atomicAdd(&logits[c0 + r], p);
    }
}

__global__ void ncde_fin(const float* __restrict__ logits,
                         const float* __restrict__ db,
                         float* __restrict__ out)
{
    int i = threadIdx.x;
    if (i < 512){
        float x = logits[i] + db[0];
        out[i] = 1.0f / (1.0f + __expf(-x));
    }
}

extern "C" void kernel_launch(void* const* d_in, const int* in_sizes, int n_in,
                              void* d_out, int out_size, void* d_ws, size_t ws_size,
                              hipStream_t stream)
{
    const float* times = (const float*)d_in[0];
    const float* xs    = (const float*)d_in[1];
    const float* eW0   = (const float*)d_in[2];
    const float* eb0   = (const float*)d_in[3];
    const float* eW1   = (const float*)d_in[4];
    const float* eb1   = (const float*)d_in[5];
    const float* eW2   = (const float*)d_in[6];
    const float* eb2   = (const float*)d_in[7];
    const float* vW0   = (const float*)d_in[8];
    const float* vb0   = (const float*)d_in[9];
    const float* vW1   = (const float*)d_in[10];
    const float* vb1   = (const float*)d_in[11];
    const float* vW2   = (const float*)d_in[12];
    const float* vb2   = (const float*)d_in[13];
    const float* dW    = (const float*)d_in[14];
    const float* db    = (const float*)d_in[15];

    // workspace layout: flags (32KB: 256 slices * 128B) | logits (2KB) | gbuf (256KB)
    unsigned* flags  = (unsigned*)d_ws;
    float*    logits = (float*)((char*)d_ws + 32768);
    float*    gbuf   = (float*)((char*)d_ws + 36864);

    hipMemsetAsync(d_ws, 0, 36864, stream);
    hipFuncSetAttribute((const void*)ncde_main,
                        hipFuncAttributeMaxDynamicSharedMemorySize, LDSB);

    ncde_main<<<dim3(256), dim3(NTH), LDSB, stream>>>(
        times, xs, eW0, eb0, eW1, eb1, eW2, eb2,
        vW0, vW1, vb0, vb1, vW2, vb2, dW,
        logits, flags, gbuf);
    ncde_fin<<<dim3(1), dim3(512), 0, stream>>>(logits, db, (float*)d_out);
}